// Round 1
// baseline (3632.239 us; speedup 1.0000x reference)
//
#include <hip/hip_runtime.h>

#define N_NODES 50000
#define N_EDGES 800000
// IN is always 128; OUT is 128,128,64.

__global__ __launch_bounds__(256) void deg_kernel(const int* __restrict__ dst,
                                                  float* __restrict__ deg, int nedges) {
    int e = blockIdx.x * 256 + threadIdx.x;
    if (e < nedges) atomicAdd(&deg[dst[e]], 1.0f);
}

__global__ __launch_bounds__(256) void norm_kernel(float* __restrict__ norm, int n) {
    int i = blockIdx.x * 256 + threadIdx.x;
    if (i < n) {
        float d = norm[i];
        norm[i] = d > 0.0f ? rsqrtf(fmaxf(d, 1.0f)) : 0.0f;
    }
}

// C[r, j] = norm[r] * sum_k X[r,k] * W[k,j]   (X is [nrows,128], W is [128,OUT])
template <int OUT>
__global__ __launch_bounds__(256) void gemm_rownorm(const float* __restrict__ X,
                                                    const float* __restrict__ W,
                                                    const float* __restrict__ norm,
                                                    float* __restrict__ C, int nrows) {
    constexpr int CG  = OUT / 4;   // threads covering the column dim (each does 4 cols)
    constexpr int RG  = 256 / CG;  // row groups per block
    constexpr int RPT = 64 / RG;   // rows per thread (block covers 64 rows)

    const int t  = threadIdx.x;
    const int tx = t % CG;
    const int ty = t / CG;
    const int rowbase = blockIdx.x * 64 + ty;  // rows: rowbase + i*RG
    const int lastrow = nrows - 1;

    float4 acc[RPT];
#pragma unroll
    for (int i = 0; i < RPT; ++i) acc[i] = make_float4(0.f, 0.f, 0.f, 0.f);

    const float4* __restrict__ W4 = reinterpret_cast<const float4*>(W);

#pragma unroll 4
    for (int kk = 0; kk < 32; ++kk) {
        const float4 w0 = W4[(4 * kk + 0) * CG + tx];
        const float4 w1 = W4[(4 * kk + 1) * CG + tx];
        const float4 w2 = W4[(4 * kk + 2) * CG + tx];
        const float4 w3 = W4[(4 * kk + 3) * CG + tx];
#pragma unroll
        for (int i = 0; i < RPT; ++i) {
            int r  = rowbase + i * RG;
            int rr = r < lastrow ? r : lastrow;  // clamp (store is guarded)
            const float4 xv = reinterpret_cast<const float4*>(X + (size_t)rr * 128)[kk];
            acc[i].x += xv.x * w0.x + xv.y * w1.x + xv.z * w2.x + xv.w * w3.x;
            acc[i].y += xv.x * w0.y + xv.y * w1.y + xv.z * w2.y + xv.w * w3.y;
            acc[i].z += xv.x * w0.z + xv.y * w1.z + xv.z * w2.z + xv.w * w3.z;
            acc[i].w += xv.x * w0.w + xv.y * w1.w + xv.z * w2.w + xv.w * w3.w;
        }
    }

#pragma unroll
    for (int i = 0; i < RPT; ++i) {
        int r = rowbase + i * RG;
        if (r < nrows) {
            const float nm = norm[r];
            float4 o = acc[i];
            o.x *= nm; o.y *= nm; o.z *= nm; o.w *= nm;
            reinterpret_cast<float4*>(C + (size_t)r * OUT)[tx] = o;
        }
    }
}

// agg[dst[e], :] += feat[src[e], :]
template <int F>
__global__ __launch_bounds__(256) void scatter_kernel(const float* __restrict__ feat,
                                                      const int* __restrict__ src,
                                                      const int* __restrict__ dst,
                                                      float* __restrict__ agg, int nedges) {
    constexpr int TPE = F / 4;  // threads per edge
    int gid = blockIdx.x * 256 + threadIdx.x;
    int e = gid / TPE;
    int f = (gid % TPE) * 4;
    if (e >= nedges) return;
    const int s = src[e];
    const int d = dst[e];
    const float4 v = *reinterpret_cast<const float4*>(&feat[(size_t)s * F + f]);
    float* o = &agg[(size_t)d * F + f];
    atomicAdd(o + 0, v.x);
    atomicAdd(o + 1, v.y);
    atomicAdd(o + 2, v.z);
    atomicAdd(o + 3, v.w);
}

// out = (RELU?) (agg * norm[r] + b[j])
template <int F, bool RELU>
__global__ __launch_bounds__(256) void epilogue_kernel(const float* __restrict__ agg,
                                                       const float* __restrict__ norm,
                                                       const float* __restrict__ b,
                                                       float* __restrict__ out, int n) {
    constexpr int C4 = F / 4;
    int gid = blockIdx.x * 256 + threadIdx.x;
    if (gid >= n * C4) return;
    int r  = gid / C4;
    int c4 = gid % C4;
    const float nm = norm[r];
    float4 v  = reinterpret_cast<const float4*>(agg)[gid];
    float4 bb = reinterpret_cast<const float4*>(b)[c4];
    float4 o;
    o.x = v.x * nm + bb.x;
    o.y = v.y * nm + bb.y;
    o.z = v.z * nm + bb.z;
    o.w = v.w * nm + bb.w;
    if (RELU) {
        o.x = fmaxf(o.x, 0.f); o.y = fmaxf(o.y, 0.f);
        o.z = fmaxf(o.z, 0.f); o.w = fmaxf(o.w, 0.f);
    }
    reinterpret_cast<float4*>(out)[gid] = o;
}

extern "C" void kernel_launch(void* const* d_in, const int* in_sizes, int n_in,
                              void* d_out, int out_size, void* d_ws, size_t ws_size,
                              hipStream_t stream) {
    const float* features = (const float*)d_in[0];
    const int*   src      = (const int*)d_in[1];
    const int*   dst      = (const int*)d_in[2];
    const float* W1 = (const float*)d_in[3];
    const float* b1 = (const float*)d_in[4];
    const float* W2 = (const float*)d_in[5];
    const float* b2 = (const float*)d_in[6];
    const float* W3 = (const float*)d_in[7];
    const float* b3 = (const float*)d_in[8];
    float* out = (float*)d_out;

    char* ws = (char*)d_ws;
    float* norm = (float*)ws;  // N floats (used as deg, then transformed in place)
    size_t off  = ((size_t)N_NODES * 4 + 255) / 256 * 256;
    float* buf0 = (float*)(ws + off);                 // N*128 floats
    float* buf1 = buf0 + (size_t)N_NODES * 128;       // N*128 floats

    const int gemm_blocks = (N_NODES + 63) / 64;

    // degrees -> norm
    hipMemsetAsync(norm, 0, (size_t)N_NODES * 4, stream);
    deg_kernel<<<(N_EDGES + 255) / 256, 256, 0, stream>>>(dst, norm, N_EDGES);
    norm_kernel<<<(N_NODES + 255) / 256, 256, 0, stream>>>(norm, N_NODES);

    // ---- Layer 1: features -> buf0 (gemm) -> buf1 (agg) -> buf0 (h1) ----
    gemm_rownorm<128><<<gemm_blocks, 256, 0, stream>>>(features, W1, norm, buf0, N_NODES);
    hipMemsetAsync(buf1, 0, (size_t)N_NODES * 128 * 4, stream);
    scatter_kernel<128><<<(N_EDGES * 32) / 256, 256, 0, stream>>>(buf0, src, dst, buf1, N_EDGES);
    epilogue_kernel<128, true><<<(N_NODES * 32 + 255) / 256, 256, 0, stream>>>(buf1, norm, b1, buf0, N_NODES);

    // ---- Layer 2: buf0 -> buf1 (gemm) -> buf0 (agg) -> buf1 (h2) ----
    gemm_rownorm<128><<<gemm_blocks, 256, 0, stream>>>(buf0, W2, norm, buf1, N_NODES);
    hipMemsetAsync(buf0, 0, (size_t)N_NODES * 128 * 4, stream);
    scatter_kernel<128><<<(N_EDGES * 32) / 256, 256, 0, stream>>>(buf1, src, dst, buf0, N_EDGES);
    epilogue_kernel<128, true><<<(N_NODES * 32 + 255) / 256, 256, 0, stream>>>(buf0, norm, b2, buf1, N_NODES);

    // ---- Layer 3: buf1 -> buf0 (gemm, 64 cols) -> d_out (agg) -> d_out ----
    gemm_rownorm<64><<<gemm_blocks, 256, 0, stream>>>(buf1, W3, norm, buf0, N_NODES);
    hipMemsetAsync(out, 0, (size_t)N_NODES * 64 * 4, stream);
    scatter_kernel<64><<<(N_EDGES * 16) / 256, 256, 0, stream>>>(buf0, src, dst, out, N_EDGES);
    epilogue_kernel<64, false><<<(N_NODES * 16 + 255) / 256, 256, 0, stream>>>(out, norm, b3, out, N_NODES);
}

// Round 2
// 587.187 us; speedup vs baseline: 6.1858x; 6.1858x over previous
//
#include <hip/hip_runtime.h>

#define N_NODES 50000
#define N_EDGES 800000
// IN is always 128; OUT is 128,128,64.

// ---------- CSR build ----------

__global__ __launch_bounds__(256) void count_kernel(const int* __restrict__ dst,
                                                    int* __restrict__ cnt, int nedges) {
    int e = blockIdx.x * 256 + threadIdx.x;
    if (e < nedges) atomicAdd(&cnt[dst[e]], 1);
}

// Single-block exclusive scan over n counts -> rowptr[0..n], cursor copy, norm.
__global__ __launch_bounds__(1024) void scan_kernel(const int* __restrict__ cnt,
                                                    int* __restrict__ rowptr,
                                                    int* __restrict__ cursor,
                                                    float* __restrict__ norm, int n) {
    __shared__ int lds[1024];
    const int tid = threadIdx.x;
    const int per = (n + 1023) / 1024;
    const int base = tid * per;

    int sum = 0;
    for (int i = 0; i < per; ++i) {
        int idx = base + i;
        if (idx < n) sum += cnt[idx];
    }
    lds[tid] = sum;
    __syncthreads();
    for (int off = 1; off < 1024; off <<= 1) {
        int add = (tid >= off) ? lds[tid - off] : 0;
        __syncthreads();
        lds[tid] += add;
        __syncthreads();
    }
    int run = (tid == 0) ? 0 : lds[tid - 1];
    for (int i = 0; i < per; ++i) {
        int idx = base + i;
        if (idx < n) {
            rowptr[idx] = run;
            cursor[idx] = run;
            int c = cnt[idx];
            norm[idx] = c > 0 ? rsqrtf((float)c) : 0.0f;
            run += c;
        }
    }
    if (tid == 1023) rowptr[n] = lds[1023];
}

__global__ __launch_bounds__(256) void fill_kernel(const int* __restrict__ src,
                                                   const int* __restrict__ dst,
                                                   int* __restrict__ cursor,
                                                   int* __restrict__ esrc, int nedges) {
    int e = blockIdx.x * 256 + threadIdx.x;
    if (e < nedges) {
        int pos = atomicAdd(&cursor[dst[e]], 1);
        esrc[pos] = src[e];
    }
}

// ---------- GEMM with output row-scale ----------
// C[r, j] = norm[r] * sum_k X[r,k] * W[k,j]   (X is [nrows,128], W is [128,OUT])
template <int OUT>
__global__ __launch_bounds__(256) void gemm_rownorm(const float* __restrict__ X,
                                                    const float* __restrict__ W,
                                                    const float* __restrict__ norm,
                                                    float* __restrict__ C, int nrows) {
    constexpr int CG  = OUT / 4;
    constexpr int RG  = 256 / CG;
    constexpr int RPT = 64 / RG;

    const int t  = threadIdx.x;
    const int tx = t % CG;
    const int ty = t / CG;
    const int rowbase = blockIdx.x * 64 + ty;
    const int lastrow = nrows - 1;

    float4 acc[RPT];
#pragma unroll
    for (int i = 0; i < RPT; ++i) acc[i] = make_float4(0.f, 0.f, 0.f, 0.f);

    const float4* __restrict__ W4 = reinterpret_cast<const float4*>(W);

#pragma unroll 4
    for (int kk = 0; kk < 32; ++kk) {
        const float4 w0 = W4[(4 * kk + 0) * CG + tx];
        const float4 w1 = W4[(4 * kk + 1) * CG + tx];
        const float4 w2 = W4[(4 * kk + 2) * CG + tx];
        const float4 w3 = W4[(4 * kk + 3) * CG + tx];
#pragma unroll
        for (int i = 0; i < RPT; ++i) {
            int r  = rowbase + i * RG;
            int rr = r < lastrow ? r : lastrow;
            const float4 xv = reinterpret_cast<const float4*>(X + (size_t)rr * 128)[kk];
            acc[i].x += xv.x * w0.x + xv.y * w1.x + xv.z * w2.x + xv.w * w3.x;
            acc[i].y += xv.x * w0.y + xv.y * w1.y + xv.z * w2.y + xv.w * w3.y;
            acc[i].z += xv.x * w0.z + xv.y * w1.z + xv.z * w2.z + xv.w * w3.z;
            acc[i].w += xv.x * w0.w + xv.y * w1.w + xv.z * w2.w + xv.w * w3.w;
        }
    }

#pragma unroll
    for (int i = 0; i < RPT; ++i) {
        int r = rowbase + i * RG;
        if (r < nrows) {
            const float nm = norm[r];
            float4 o = acc[i];
            o.x *= nm; o.y *= nm; o.z *= nm; o.w *= nm;
            reinterpret_cast<float4*>(C + (size_t)r * OUT)[tx] = o;
        }
    }
}

// ---------- Fused gather-aggregate + epilogue ----------
// One 64-lane wave per node: out[n,:] = act(norm[n] * sum_{e in in(n)} feat[esrc[e],:] + b)
template <int F, bool RELU>
__global__ __launch_bounds__(256) void aggregate_kernel(const float* __restrict__ feat,
                                                        const int* __restrict__ rowptr,
                                                        const int* __restrict__ esrc,
                                                        const float* __restrict__ norm,
                                                        const float* __restrict__ b,
                                                        float* __restrict__ out, int nnodes) {
    const int wave = (blockIdx.x * 256 + threadIdx.x) >> 6;
    const int lane = threadIdx.x & 63;
    if (wave >= nnodes) return;

    const int beg = rowptr[wave];
    const int end = rowptr[wave + 1];

    if constexpr (F == 128) {
        const float2* __restrict__ feat2 = reinterpret_cast<const float2*>(feat);
        float ax = 0.f, ay = 0.f;
        int e = beg;
        for (; e + 1 < end; e += 2) {
            int s0 = esrc[e];
            int s1 = esrc[e + 1];
            float2 v0 = feat2[(size_t)s0 * 64 + lane];
            float2 v1 = feat2[(size_t)s1 * 64 + lane];
            ax += v0.x + v1.x;
            ay += v0.y + v1.y;
        }
        if (e < end) {
            int s0 = esrc[e];
            float2 v0 = feat2[(size_t)s0 * 64 + lane];
            ax += v0.x;
            ay += v0.y;
        }
        const float nm = norm[wave];
        const float2 bb = reinterpret_cast<const float2*>(b)[lane];
        float ox = ax * nm + bb.x;
        float oy = ay * nm + bb.y;
        if (RELU) { ox = fmaxf(ox, 0.f); oy = fmaxf(oy, 0.f); }
        reinterpret_cast<float2*>(out)[(size_t)wave * 64 + lane] = make_float2(ox, oy);
    } else {
        float acc = 0.f;
        int e = beg;
        for (; e + 1 < end; e += 2) {
            int s0 = esrc[e];
            int s1 = esrc[e + 1];
            acc += feat[(size_t)s0 * F + lane] + feat[(size_t)s1 * F + lane];
        }
        if (e < end) acc += feat[(size_t)esrc[e] * F + lane];
        const float nm = norm[wave];
        float o = acc * nm + b[lane];
        if (RELU) o = fmaxf(o, 0.f);
        out[(size_t)wave * F + lane] = o;
    }
}

extern "C" void kernel_launch(void* const* d_in, const int* in_sizes, int n_in,
                              void* d_out, int out_size, void* d_ws, size_t ws_size,
                              hipStream_t stream) {
    const float* features = (const float*)d_in[0];
    const int*   src      = (const int*)d_in[1];
    const int*   dst      = (const int*)d_in[2];
    const float* W1 = (const float*)d_in[3];
    const float* b1 = (const float*)d_in[4];
    const float* W2 = (const float*)d_in[5];
    const float* b2 = (const float*)d_in[6];
    const float* W3 = (const float*)d_in[7];
    const float* b3 = (const float*)d_in[8];
    float* out = (float*)d_out;

    auto align256 = [](size_t x) { return (x + 255) / 256 * 256; };
    char* ws = (char*)d_ws;
    size_t off = 0;
    float* norm   = (float*)(ws + off); off += align256((size_t)N_NODES * 4);
    int*   cnt    = (int*)(ws + off);   off += align256((size_t)N_NODES * 4);
    int*   cursor = (int*)(ws + off);   off += align256((size_t)N_NODES * 4);
    int*   rowptr = (int*)(ws + off);   off += align256(((size_t)N_NODES + 1) * 4);
    int*   esrc   = (int*)(ws + off);   off += align256((size_t)N_EDGES * 4);
    float* buf0   = (float*)(ws + off); off += (size_t)N_NODES * 128 * 4;
    float* buf1   = (float*)(ws + off);

    const int gemm_blocks = (N_NODES + 63) / 64;
    const int agg_blocks  = (N_NODES * 64 + 255) / 256;
    const int edge_blocks = (N_EDGES + 255) / 256;

    // ---- CSR build + norm ----
    hipMemsetAsync(cnt, 0, (size_t)N_NODES * 4, stream);
    count_kernel<<<edge_blocks, 256, 0, stream>>>(dst, cnt, N_EDGES);
    scan_kernel<<<1, 1024, 0, stream>>>(cnt, rowptr, cursor, norm, N_NODES);
    fill_kernel<<<edge_blocks, 256, 0, stream>>>(src, dst, cursor, esrc, N_EDGES);

    // ---- Layer 1: features -> buf0 (gemm) -> buf1 (h1) ----
    gemm_rownorm<128><<<gemm_blocks, 256, 0, stream>>>(features, W1, norm, buf0, N_NODES);
    aggregate_kernel<128, true><<<agg_blocks, 256, 0, stream>>>(buf0, rowptr, esrc, norm, b1, buf1, N_NODES);

    // ---- Layer 2: buf1 -> buf0 (gemm) -> buf1 (h2) ----
    gemm_rownorm<128><<<gemm_blocks, 256, 0, stream>>>(buf1, W2, norm, buf0, N_NODES);
    aggregate_kernel<128, true><<<agg_blocks, 256, 0, stream>>>(buf0, rowptr, esrc, norm, b2, buf1, N_NODES);

    // ---- Layer 3: buf1 -> buf0 (gemm, 64 cols) -> d_out ----
    gemm_rownorm<64><<<gemm_blocks, 256, 0, stream>>>(buf1, W3, norm, buf0, N_NODES);
    aggregate_kernel<64, false><<<agg_blocks, 256, 0, stream>>>(buf0, rowptr, esrc, norm, b3, out, N_NODES);
}

// Round 3
// 428.555 us; speedup vs baseline: 8.4756x; 1.3702x over previous
//
#include <hip/hip_runtime.h>

#define N_NODES 50000
#define N_EDGES 800000
#define SCAN_NB ((N_NODES + 255) / 256)

// ---------- CSR build ----------

__global__ __launch_bounds__(256) void count_kernel(const int* __restrict__ dst,
                                                    int* __restrict__ cnt, int nedges) {
    int e = blockIdx.x * 256 + threadIdx.x;
    if (e < nedges) atomicAdd(&cnt[dst[e]], 1);
}

__device__ __forceinline__ int wave_incl_scan(int v, int lane) {
#pragma unroll
    for (int off = 1; off < 64; off <<= 1) {
        int t = __shfl_up(v, off, 64);
        if (lane >= off) v += t;
    }
    return v;
}

// Per-256-block sums of cnt.
__global__ __launch_bounds__(256) void scanA_kernel(const int* __restrict__ cnt,
                                                    int* __restrict__ partials, int n) {
    const int i = blockIdx.x * 256 + threadIdx.x;
    const int lane = threadIdx.x & 63;
    const int w = threadIdx.x >> 6;
    int v = (i < n) ? cnt[i] : 0;
    int s = wave_incl_scan(v, lane);
    __shared__ int ws[4];
    if (lane == 63) ws[w] = s;
    __syncthreads();
    if (threadIdx.x == 0) partials[blockIdx.x] = ws[0] + ws[1] + ws[2] + ws[3];
}

// Exclusive scan of the partials (one block; SCAN_NB <= 256).
__global__ __launch_bounds__(256) void scanB_kernel(int* __restrict__ partials, int nb) {
    const int i = threadIdx.x;
    const int lane = i & 63;
    const int w = i >> 6;
    int v = (i < nb) ? partials[i] : 0;
    int s = wave_incl_scan(v, lane);
    __shared__ int ws[4];
    if (lane == 63) ws[w] = s;
    __syncthreads();
    int add = 0;
#pragma unroll
    for (int k = 0; k < 4; ++k)
        if (k < w) add += ws[k];
    if (i < nb) partials[i] = s + add - v;  // exclusive
}

// Recompute local scan + block offset -> rowptr/cursor/norm.
__global__ __launch_bounds__(256) void scanC_kernel(const int* __restrict__ cnt,
                                                    const int* __restrict__ partials,
                                                    int* __restrict__ rowptr,
                                                    int* __restrict__ cursor,
                                                    float* __restrict__ norm, int n) {
    const int i = blockIdx.x * 256 + threadIdx.x;
    const int lane = threadIdx.x & 63;
    const int w = threadIdx.x >> 6;
    int v = (i < n) ? cnt[i] : 0;
    int s = wave_incl_scan(v, lane);
    __shared__ int ws[4];
    if (lane == 63) ws[w] = s;
    __syncthreads();
    int add = partials[blockIdx.x];
#pragma unroll
    for (int k = 0; k < 4; ++k)
        if (k < w) add += ws[k];
    if (i < n) {
        int excl = s + add - v;
        rowptr[i] = excl;
        cursor[i] = excl;
        norm[i] = v > 0 ? rsqrtf((float)v) : 0.0f;
        if (i == n - 1) rowptr[n] = excl + v;
    }
}

__global__ __launch_bounds__(256) void fill_kernel(const int* __restrict__ src,
                                                   const int* __restrict__ dst,
                                                   int* __restrict__ cursor,
                                                   int* __restrict__ esrc, int nedges) {
    int e = blockIdx.x * 256 + threadIdx.x;
    if (e < nedges) {
        int pos = atomicAdd(&cursor[dst[e]], 1);
        esrc[pos] = src[e];
    }
}

// ---------- GEMM with output row-scale ----------
// C[r, j] = norm[r] * sum_k X[r,k] * W[k,j]
template <int OUT>
__global__ __launch_bounds__(256) void gemm_rownorm(const float* __restrict__ X,
                                                    const float* __restrict__ W,
                                                    const float* __restrict__ norm,
                                                    float* __restrict__ C, int nrows) {
    constexpr int CG  = OUT / 4;
    constexpr int RG  = 256 / CG;
    constexpr int RPT = 64 / RG;

    const int t  = threadIdx.x;
    const int tx = t % CG;
    const int ty = t / CG;
    const int rowbase = blockIdx.x * 64 + ty;
    const int lastrow = nrows - 1;

    float4 acc[RPT];
#pragma unroll
    for (int i = 0; i < RPT; ++i) acc[i] = make_float4(0.f, 0.f, 0.f, 0.f);

    const float4* __restrict__ W4 = reinterpret_cast<const float4*>(W);

#pragma unroll 4
    for (int kk = 0; kk < 32; ++kk) {
        const float4 w0 = W4[(4 * kk + 0) * CG + tx];
        const float4 w1 = W4[(4 * kk + 1) * CG + tx];
        const float4 w2 = W4[(4 * kk + 2) * CG + tx];
        const float4 w3 = W4[(4 * kk + 3) * CG + tx];
#pragma unroll
        for (int i = 0; i < RPT; ++i) {
            int r  = rowbase + i * RG;
            int rr = r < lastrow ? r : lastrow;
            const float4 xv = reinterpret_cast<const float4*>(X + (size_t)rr * 128)[kk];
            acc[i].x += xv.x * w0.x + xv.y * w1.x + xv.z * w2.x + xv.w * w3.x;
            acc[i].y += xv.x * w0.y + xv.y * w1.y + xv.z * w2.y + xv.w * w3.y;
            acc[i].z += xv.x * w0.z + xv.y * w1.z + xv.z * w2.z + xv.w * w3.z;
            acc[i].w += xv.x * w0.w + xv.y * w1.w + xv.z * w2.w + xv.w * w3.w;
        }
    }

#pragma unroll
    for (int i = 0; i < RPT; ++i) {
        int r = rowbase + i * RG;
        if (r < nrows) {
            const float nm = norm[r];
            float4 o = acc[i];
            o.x *= nm; o.y *= nm; o.z *= nm; o.w *= nm;
            reinterpret_cast<float4*>(C + (size_t)r * OUT)[tx] = o;
        }
    }
}

// ---------- Fused gather-aggregate + epilogue ----------
// One 64-lane wave per node: out[n,:] = act(norm[n] * sum_{e in in(n)} feat[esrc[e],:] + b)
template <int F, bool RELU>
__global__ __launch_bounds__(256) void aggregate_kernel(const float* __restrict__ feat,
                                                        const int* __restrict__ rowptr,
                                                        const int* __restrict__ esrc,
                                                        const float* __restrict__ norm,
                                                        const float* __restrict__ b,
                                                        float* __restrict__ out, int nnodes) {
    const int wave = (blockIdx.x * 256 + threadIdx.x) >> 6;
    const int lane = threadIdx.x & 63;
    if (wave >= nnodes) return;

    const int beg = rowptr[wave];
    const int end = rowptr[wave + 1];

    if constexpr (F == 128) {
        const float2* __restrict__ feat2 = reinterpret_cast<const float2*>(feat);
        float ax = 0.f, ay = 0.f;
        int e = beg;
        for (; e + 3 < end; e += 4) {
            int s0 = esrc[e + 0];
            int s1 = esrc[e + 1];
            int s2 = esrc[e + 2];
            int s3 = esrc[e + 3];
            float2 v0 = feat2[(size_t)s0 * 64 + lane];
            float2 v1 = feat2[(size_t)s1 * 64 + lane];
            float2 v2 = feat2[(size_t)s2 * 64 + lane];
            float2 v3 = feat2[(size_t)s3 * 64 + lane];
            ax += (v0.x + v1.x) + (v2.x + v3.x);
            ay += (v0.y + v1.y) + (v2.y + v3.y);
        }
        for (; e < end; ++e) {
            float2 v0 = feat2[(size_t)esrc[e] * 64 + lane];
            ax += v0.x;
            ay += v0.y;
        }
        const float nm = norm[wave];
        const float2 bb = reinterpret_cast<const float2*>(b)[lane];
        float ox = ax * nm + bb.x;
        float oy = ay * nm + bb.y;
        if (RELU) { ox = fmaxf(ox, 0.f); oy = fmaxf(oy, 0.f); }
        reinterpret_cast<float2*>(out)[(size_t)wave * 64 + lane] = make_float2(ox, oy);
    } else {
        float acc = 0.f;
        int e = beg;
        for (; e + 3 < end; e += 4) {
            int s0 = esrc[e + 0];
            int s1 = esrc[e + 1];
            int s2 = esrc[e + 2];
            int s3 = esrc[e + 3];
            acc += (feat[(size_t)s0 * F + lane] + feat[(size_t)s1 * F + lane]) +
                   (feat[(size_t)s2 * F + lane] + feat[(size_t)s3 * F + lane]);
        }
        for (; e < end; ++e) acc += feat[(size_t)esrc[e] * F + lane];
        const float nm = norm[wave];
        float o = acc * nm + b[lane];
        if (RELU) o = fmaxf(o, 0.f);
        out[(size_t)wave * F + lane] = o;
    }
}

extern "C" void kernel_launch(void* const* d_in, const int* in_sizes, int n_in,
                              void* d_out, int out_size, void* d_ws, size_t ws_size,
                              hipStream_t stream) {
    const float* features = (const float*)d_in[0];
    const int*   src      = (const int*)d_in[1];
    const int*   dst      = (const int*)d_in[2];
    const float* W1 = (const float*)d_in[3];
    const float* b1 = (const float*)d_in[4];
    const float* W2 = (const float*)d_in[5];
    const float* b2 = (const float*)d_in[6];
    const float* W3 = (const float*)d_in[7];
    const float* b3 = (const float*)d_in[8];
    float* out = (float*)d_out;

    auto align256 = [](size_t x) { return (x + 255) / 256 * 256; };
    char* ws = (char*)d_ws;
    size_t off = 0;
    float* norm     = (float*)(ws + off); off += align256((size_t)N_NODES * 4);
    int*   cnt      = (int*)(ws + off);   off += align256((size_t)N_NODES * 4);
    int*   cursor   = (int*)(ws + off);   off += align256((size_t)N_NODES * 4);
    int*   rowptr   = (int*)(ws + off);   off += align256(((size_t)N_NODES + 1) * 4);
    int*   partials = (int*)(ws + off);   off += align256((size_t)SCAN_NB * 4);
    int*   esrc     = (int*)(ws + off);   off += align256((size_t)N_EDGES * 4);
    float* buf0     = (float*)(ws + off); off += (size_t)N_NODES * 128 * 4;
    float* buf1     = (float*)(ws + off);

    const int gemm_blocks = (N_NODES + 63) / 64;
    const int agg_blocks  = (N_NODES * 64 + 255) / 256;
    const int edge_blocks = (N_EDGES + 255) / 256;

    // ---- CSR build + norm ----
    hipMemsetAsync(cnt, 0, (size_t)N_NODES * 4, stream);
    count_kernel<<<edge_blocks, 256, 0, stream>>>(dst, cnt, N_EDGES);
    scanA_kernel<<<SCAN_NB, 256, 0, stream>>>(cnt, partials, N_NODES);
    scanB_kernel<<<1, 256, 0, stream>>>(partials, SCAN_NB);
    scanC_kernel<<<SCAN_NB, 256, 0, stream>>>(cnt, partials, rowptr, cursor, norm, N_NODES);
    fill_kernel<<<edge_blocks, 256, 0, stream>>>(src, dst, cursor, esrc, N_EDGES);

    // ---- Layer 1: features -> buf0 (gemm) -> buf1 (h1) ----
    gemm_rownorm<128><<<gemm_blocks, 256, 0, stream>>>(features, W1, norm, buf0, N_NODES);
    aggregate_kernel<128, true><<<agg_blocks, 256, 0, stream>>>(buf0, rowptr, esrc, norm, b1, buf1, N_NODES);

    // ---- Layer 2: buf1 -> buf0 (gemm) -> buf1 (h2) ----
    gemm_rownorm<128><<<gemm_blocks, 256, 0, stream>>>(buf1, W2, norm, buf0, N_NODES);
    aggregate_kernel<128, true><<<agg_blocks, 256, 0, stream>>>(buf0, rowptr, esrc, norm, b2, buf1, N_NODES);

    // ---- Layer 3: buf1 -> buf0 (gemm, 64 cols) -> d_out ----
    gemm_rownorm<64><<<gemm_blocks, 256, 0, stream>>>(buf1, W3, norm, buf0, N_NODES);
    aggregate_kernel<64, false><<<agg_blocks, 256, 0, stream>>>(buf0, rowptr, esrc, norm, b3, out, N_NODES);
}

// Round 4
// 330.686 us; speedup vs baseline: 10.9840x; 1.2960x over previous
//
#include <hip/hip_runtime.h>

#define N_NODES 50000
#define N_EDGES 800000
#define SCAN_NB ((N_NODES + 255) / 256)

// ---------- CSR build ----------

__global__ __launch_bounds__(256) void count_kernel(const int* __restrict__ dst,
                                                    int* __restrict__ cnt, int nedges) {
    int e = blockIdx.x * 256 + threadIdx.x;
    if (e < nedges) atomicAdd(&cnt[dst[e]], 1);
}

__device__ __forceinline__ int wave_incl_scan(int v, int lane) {
#pragma unroll
    for (int off = 1; off < 64; off <<= 1) {
        int t = __shfl_up(v, off, 64);
        if (lane >= off) v += t;
    }
    return v;
}

__global__ __launch_bounds__(256) void scanA_kernel(const int* __restrict__ cnt,
                                                    int* __restrict__ partials, int n) {
    const int i = blockIdx.x * 256 + threadIdx.x;
    const int lane = threadIdx.x & 63;
    const int w = threadIdx.x >> 6;
    int v = (i < n) ? cnt[i] : 0;
    int s = wave_incl_scan(v, lane);
    __shared__ int ws[4];
    if (lane == 63) ws[w] = s;
    __syncthreads();
    if (threadIdx.x == 0) partials[blockIdx.x] = ws[0] + ws[1] + ws[2] + ws[3];
}

__global__ __launch_bounds__(256) void scanB_kernel(int* __restrict__ partials, int nb) {
    const int i = threadIdx.x;
    const int lane = i & 63;
    const int w = i >> 6;
    int v = (i < nb) ? partials[i] : 0;
    int s = wave_incl_scan(v, lane);
    __shared__ int ws[4];
    if (lane == 63) ws[w] = s;
    __syncthreads();
    int add = 0;
#pragma unroll
    for (int k = 0; k < 4; ++k)
        if (k < w) add += ws[k];
    if (i < nb) partials[i] = s + add - v;  // exclusive
}

__global__ __launch_bounds__(256) void scanC_kernel(const int* __restrict__ cnt,
                                                    const int* __restrict__ partials,
                                                    int* __restrict__ rowptr,
                                                    int* __restrict__ cursor,
                                                    float* __restrict__ norm, int n) {
    const int i = blockIdx.x * 256 + threadIdx.x;
    const int lane = threadIdx.x & 63;
    const int w = threadIdx.x >> 6;
    int v = (i < n) ? cnt[i] : 0;
    int s = wave_incl_scan(v, lane);
    __shared__ int ws[4];
    if (lane == 63) ws[w] = s;
    __syncthreads();
    int add = partials[blockIdx.x];
#pragma unroll
    for (int k = 0; k < 4; ++k)
        if (k < w) add += ws[k];
    if (i < n) {
        int excl = s + add - v;
        rowptr[i] = excl;
        cursor[i] = excl;
        norm[i] = v > 0 ? rsqrtf((float)v) : 0.0f;
        if (i == n - 1) rowptr[n] = excl + v;
    }
}

__global__ __launch_bounds__(256) void fill_kernel(const int* __restrict__ src,
                                                   const int* __restrict__ dst,
                                                   int* __restrict__ cursor,
                                                   int* __restrict__ esrc, int nedges) {
    int e = blockIdx.x * 256 + threadIdx.x;
    if (e < nedges) {
        int pos = atomicAdd(&cursor[dst[e]], 1);
        esrc[pos] = src[e];
    }
}

// ---------- GEMM with output row-scale, W staged in LDS ----------
// C[r, j] = norm[r] * sum_k X[r,k] * W[k,j]   (X: [nrows,128], W: [128,OUT])
// Block: 256 threads, 128 rows. Thread: 8 rows x (OUT=128 ? 8 : 4) cols.
template <int OUT>
__global__ __launch_bounds__(256) void gemm_rownorm(const float* __restrict__ X,
                                                    const float* __restrict__ W,
                                                    const float* __restrict__ norm,
                                                    float* __restrict__ C, int nrows) {
    __shared__ float Wlds[128 * OUT];

    const int t = threadIdx.x;

    // Stage W into LDS (once; amortized over 32 k-steps).
    constexpr int NSTAGE = (128 * OUT) / (256 * 4);  // float4s per thread: 16 or 8
    {
        const float4* __restrict__ Wg = reinterpret_cast<const float4*>(W);
        float4* Wl = reinterpret_cast<float4*>(Wlds);
#pragma unroll
        for (int s = 0; s < NSTAGE; ++s) {
            int idx = s * 256 + t;
            Wl[idx] = Wg[idx];
        }
    }
    __syncthreads();

    const int tc = t & 15;   // 16 col-groups
    const int tr = t >> 4;   // 16 row-groups
    const int rowbase = blockIdx.x * 128 + tr * 8;
    const int lastrow = nrows - 1;

    float4 acc0[8], acc1[8];
#pragma unroll
    for (int i = 0; i < 8; ++i) {
        acc0[i] = make_float4(0.f, 0.f, 0.f, 0.f);
        acc1[i] = make_float4(0.f, 0.f, 0.f, 0.f);
    }

    const float4* __restrict__ X4 = reinterpret_cast<const float4*>(X);
    int rIdx[8];
#pragma unroll
    for (int i = 0; i < 8; ++i) {
        int r = rowbase + i;
        rIdx[i] = r < lastrow ? r : lastrow;  // clamp loads; stores guarded
    }

    for (int kk = 0; kk < 32; ++kk) {
        float4 x[8];
#pragma unroll
        for (int i = 0; i < 8; ++i) x[i] = X4[(size_t)rIdx[i] * 32 + kk];
#pragma unroll
        for (int j = 0; j < 4; ++j) {
            const int k = kk * 4 + j;
            const float4 w0 = *reinterpret_cast<const float4*>(&Wlds[k * OUT + tc * 4]);
            float4 w1;
            if constexpr (OUT == 128)
                w1 = *reinterpret_cast<const float4*>(&Wlds[k * OUT + 64 + tc * 4]);
#pragma unroll
            for (int i = 0; i < 8; ++i) {
                const float* xp = reinterpret_cast<const float*>(&x[i]);
                const float xs = xp[j];
                acc0[i].x += xs * w0.x;
                acc0[i].y += xs * w0.y;
                acc0[i].z += xs * w0.z;
                acc0[i].w += xs * w0.w;
                if constexpr (OUT == 128) {
                    acc1[i].x += xs * w1.x;
                    acc1[i].y += xs * w1.y;
                    acc1[i].z += xs * w1.z;
                    acc1[i].w += xs * w1.w;
                }
            }
        }
    }

#pragma unroll
    for (int i = 0; i < 8; ++i) {
        int r = rowbase + i;
        if (r < nrows) {
            const float nm = norm[r];
            float4* Cr = reinterpret_cast<float4*>(C + (size_t)r * OUT);
            float4 o0 = acc0[i];
            o0.x *= nm; o0.y *= nm; o0.z *= nm; o0.w *= nm;
            Cr[tc] = o0;
            if constexpr (OUT == 128) {
                float4 o1 = acc1[i];
                o1.x *= nm; o1.y *= nm; o1.z *= nm; o1.w *= nm;
                Cr[16 + tc] = o1;
            }
        }
    }
}

// ---------- Fused gather-aggregate + epilogue ----------
// One 64-lane wave per node: out[n,:] = act(norm[n] * sum_{e in in(n)} feat[esrc[e],:] + b)
template <int F, bool RELU>
__global__ __launch_bounds__(256) void aggregate_kernel(const float* __restrict__ feat,
                                                        const int* __restrict__ rowptr,
                                                        const int* __restrict__ esrc,
                                                        const float* __restrict__ norm,
                                                        const float* __restrict__ b,
                                                        float* __restrict__ out, int nnodes) {
    const int wave = (blockIdx.x * 256 + threadIdx.x) >> 6;
    const int lane = threadIdx.x & 63;
    if (wave >= nnodes) return;

    const int beg = rowptr[wave];
    const int end = rowptr[wave + 1];

    if constexpr (F == 128) {
        const float2* __restrict__ feat2 = reinterpret_cast<const float2*>(feat);
        float ax = 0.f, ay = 0.f;
        int e = beg;
        for (; e + 3 < end; e += 4) {
            int s0 = esrc[e + 0];
            int s1 = esrc[e + 1];
            int s2 = esrc[e + 2];
            int s3 = esrc[e + 3];
            float2 v0 = feat2[(size_t)s0 * 64 + lane];
            float2 v1 = feat2[(size_t)s1 * 64 + lane];
            float2 v2 = feat2[(size_t)s2 * 64 + lane];
            float2 v3 = feat2[(size_t)s3 * 64 + lane];
            ax += (v0.x + v1.x) + (v2.x + v3.x);
            ay += (v0.y + v1.y) + (v2.y + v3.y);
        }
        for (; e < end; ++e) {
            float2 v0 = feat2[(size_t)esrc[e] * 64 + lane];
            ax += v0.x;
            ay += v0.y;
        }
        const float nm = norm[wave];
        const float2 bb = reinterpret_cast<const float2*>(b)[lane];
        float ox = ax * nm + bb.x;
        float oy = ay * nm + bb.y;
        if (RELU) { ox = fmaxf(ox, 0.f); oy = fmaxf(oy, 0.f); }
        reinterpret_cast<float2*>(out)[(size_t)wave * 64 + lane] = make_float2(ox, oy);
    } else {
        float acc = 0.f;
        int e = beg;
        for (; e + 3 < end; e += 4) {
            int s0 = esrc[e + 0];
            int s1 = esrc[e + 1];
            int s2 = esrc[e + 2];
            int s3 = esrc[e + 3];
            acc += (feat[(size_t)s0 * F + lane] + feat[(size_t)s1 * F + lane]) +
                   (feat[(size_t)s2 * F + lane] + feat[(size_t)s3 * F + lane]);
        }
        for (; e < end; ++e) acc += feat[(size_t)esrc[e] * F + lane];
        const float nm = norm[wave];
        float o = acc * nm + b[lane];
        if (RELU) o = fmaxf(o, 0.f);
        out[(size_t)wave * F + lane] = o;
    }
}

extern "C" void kernel_launch(void* const* d_in, const int* in_sizes, int n_in,
                              void* d_out, int out_size, void* d_ws, size_t ws_size,
                              hipStream_t stream) {
    const float* features = (const float*)d_in[0];
    const int*   src      = (const int*)d_in[1];
    const int*   dst      = (const int*)d_in[2];
    const float* W1 = (const float*)d_in[3];
    const float* b1 = (const float*)d_in[4];
    const float* W2 = (const float*)d_in[5];
    const float* b2 = (const float*)d_in[6];
    const float* W3 = (const float*)d_in[7];
    const float* b3 = (const float*)d_in[8];
    float* out = (float*)d_out;

    auto align256 = [](size_t x) { return (x + 255) / 256 * 256; };
    char* ws = (char*)d_ws;
    size_t off = 0;
    float* norm     = (float*)(ws + off); off += align256((size_t)N_NODES * 4);
    int*   cnt      = (int*)(ws + off);   off += align256((size_t)N_NODES * 4);
    int*   cursor   = (int*)(ws + off);   off += align256((size_t)N_NODES * 4);
    int*   rowptr   = (int*)(ws + off);   off += align256(((size_t)N_NODES + 1) * 4);
    int*   partials = (int*)(ws + off);   off += align256((size_t)SCAN_NB * 4);
    int*   esrc     = (int*)(ws + off);   off += align256((size_t)N_EDGES * 4);
    float* buf0     = (float*)(ws + off); off += (size_t)N_NODES * 128 * 4;
    float* buf1     = (float*)(ws + off);

    const int gemm_blocks = (N_NODES + 127) / 128;
    const int agg_blocks  = (N_NODES * 64 + 255) / 256;
    const int edge_blocks = (N_EDGES + 255) / 256;

    // ---- CSR build + norm ----
    hipMemsetAsync(cnt, 0, (size_t)N_NODES * 4, stream);
    count_kernel<<<edge_blocks, 256, 0, stream>>>(dst, cnt, N_EDGES);
    scanA_kernel<<<SCAN_NB, 256, 0, stream>>>(cnt, partials, N_NODES);
    scanB_kernel<<<1, 256, 0, stream>>>(partials, SCAN_NB);
    scanC_kernel<<<SCAN_NB, 256, 0, stream>>>(cnt, partials, rowptr, cursor, norm, N_NODES);
    fill_kernel<<<edge_blocks, 256, 0, stream>>>(src, dst, cursor, esrc, N_EDGES);

    // ---- Layer 1: features -> buf0 (gemm) -> buf1 (h1) ----
    gemm_rownorm<128><<<gemm_blocks, 256, 0, stream>>>(features, W1, norm, buf0, N_NODES);
    aggregate_kernel<128, true><<<agg_blocks, 256, 0, stream>>>(buf0, rowptr, esrc, norm, b1, buf1, N_NODES);

    // ---- Layer 2: buf1 -> buf0 (gemm) -> buf1 (h2) ----
    gemm_rownorm<128><<<gemm_blocks, 256, 0, stream>>>(buf1, W2, norm, buf0, N_NODES);
    aggregate_kernel<128, true><<<agg_blocks, 256, 0, stream>>>(buf0, rowptr, esrc, norm, b2, buf1, N_NODES);

    // ---- Layer 3: buf1 -> buf0 (gemm, 64 cols) -> d_out ----
    gemm_rownorm<64><<<gemm_blocks, 256, 0, stream>>>(buf1, W3, norm, buf0, N_NODES);
    aggregate_kernel<64, false><<<agg_blocks, 256, 0, stream>>>(buf0, rowptr, esrc, norm, b3, out, N_NODES);
}